// Round 10
// baseline (260.673 us; speedup 1.0000x reference)
//
#include <hip/hip_runtime.h>
#include <hip/hip_bf16.h>

// MPNN fused pipeline. R10 = R9 + two changes:
//  1) fused_simagg: 768-thread blocks = 4 producer + 8 consumer waves.
//     Consumer n-strip halves (64->32) -> agg 64->32 AGPRs/wave; declared
//     regs ~<=85 via __launch_bounds__(768,6) -> 6 waves/SIMD bracket
//     (2 blocks/CU x 12 waves = 24 waves/CU, 1.5x R9's residency).
//     Producer path unchanged (fp8 QK, dbuf DMA staging, 1 barrier/tile).
//  2) final GEMM reduces partial pairs during As staging (bf16 add of
//     h[c]+h[c+256]) -> K 1280->768, Wto without row duplication.
// Spill tripwire: FETCH_SIZE >> 20MB means launch_bounds squeezed too hard.

typedef short bf16x8  __attribute__((ext_vector_type(8)));
typedef short short4v __attribute__((ext_vector_type(4)));
typedef float f32x4   __attribute__((ext_vector_type(4)));

__device__ inline short f2bf(float x) {                // fp32 -> bf16 RNE
    unsigned u = __builtin_bit_cast(unsigned, x);
    return (short)((u + 0x7fffu + ((u >> 16) & 1u)) >> 16);
}
__device__ inline float bf2f(short b) {
    return __builtin_bit_cast(float, (unsigned)((unsigned short)b) << 16);
}
__device__ inline void cp16_async(const char* g, char* l) {
    __builtin_amdgcn_global_load_lds(
        (const __attribute__((address_space(1))) unsigned int*)g,
        (__attribute__((address_space(3))) unsigned int*)l, 16, 0, 0);
}

// ------------------------------------------------------------------ prep_all
// All blocks: edge_x fp32 -> bf16 h[:,0:256] + Xt [256][8192].
// Blocks (x<8,y<8) additionally loop the 5 weight transposes (Wto ld=768).
__global__ void prep_all(const float* __restrict__ X, short* __restrict__ h,
                         int ldh, short* __restrict__ Xt,
                         const float* __restrict__ W1, const float* __restrict__ W2,
                         const float* __restrict__ Wo,
                         short* __restrict__ Wt1, short* __restrict__ Wt2,
                         short* __restrict__ Wto)
{
    __shared__ short tile[32][33];
    const int tx = threadIdx.x, ty = threadIdx.y;      // 32 x 8
    {
        const int r0 = blockIdx.x * 32, c0 = blockIdx.y * 32;
        #pragma unroll
        for (int i = 0; i < 4; ++i) {
            int row = ty + i * 8;
            short b = f2bf(X[(size_t)(r0 + row) * 256 + c0 + tx]);
            tile[row][tx] = b;
            h[(size_t)(r0 + row) * ldh + c0 + tx] = b;
        }
        __syncthreads();
        #pragma unroll
        for (int i = 0; i < 4; ++i) {
            int row = ty + i * 8;
            Xt[(size_t)(c0 + row) * 8192 + r0 + tx] = tile[tx][row];
        }
    }
    if (blockIdx.x < 8 && blockIdx.y < 8) {
        const int k0 = blockIdx.x * 32, n0 = blockIdx.y * 32;
        for (int z = 0; z < 5; ++z) {
            const float* src; short* dst; int ldwt, k_off;
            if (z == 0)      { src = W1; dst = Wt1; ldwt = 256; k_off = 0; }
            else if (z == 1) { src = W2; dst = Wt2; ldwt = 256; k_off = 0; }
            else {
                int g = z - 2;                  // 0..2 -> Wo rows g*256
                src = Wo + (size_t)g * 256 * 256; dst = Wto; ldwt = 768; k_off = g * 256;
            }
            __syncthreads();
            #pragma unroll
            for (int i = 0; i < 4; ++i) {
                int row = ty + i * 8;
                tile[row][tx] = f2bf(src[(size_t)(k0 + row) * 256 + n0 + tx]);
            }
            __syncthreads();
            #pragma unroll
            for (int i = 0; i < 4; ++i) {
                int row = ty + i * 8;
                dst[(size_t)(n0 + row) * ldwt + k_off + k0 + tx] = tile[tx][row];
            }
        }
    }
}

// -------------------------------------------------------- gemm_bias_relu
// pairadd: conceptual A col c (c>=256) = h[cc] + h[cc+256], cc = c + (c<512?0:256)
__global__ __launch_bounds__(256, 1)
void gemm_bias_relu(const short* __restrict__ A, int lda,
                    const short* __restrict__ Bt0, const short* __restrict__ Bt1,
                    int K,
                    const float* __restrict__ bias0, const float* __restrict__ bias1,
                    void* __restrict__ out0, void* __restrict__ out1,
                    int out_bf16, int ldo, int swz, int pairadd)
{
    const short* Bt   = blockIdx.z ? Bt1   : Bt0;
    const float* bias = blockIdx.z ? bias1 : bias0;
    void*        outp = blockIdx.z ? out1  : out0;

    const int m0 = blockIdx.x * 64, n0 = blockIdx.y * 64;
    const int t = threadIdx.x;
    const int w = t >> 6, l = t & 63, lr = l & 15, q = l >> 4;

    __shared__ __attribute__((aligned(16))) short As[64 * 64];
    __shared__ __attribute__((aligned(16))) short Bs[64 * 64];

    f32x4 acc[4];
    #pragma unroll
    for (int i = 0; i < 4; ++i) acc[i] = f32x4{0.f, 0.f, 0.f, 0.f};

    for (int k0 = 0; k0 < K; k0 += 64) {
        __syncthreads();
        for (int i = t; i < 64 * 8; i += 256) {
            int row = i >> 3, g = i & 7;
            int c = k0 + g * 8;
            bf16x8 av;
            if (!pairadd || c < 256) {
                av = *(const bf16x8*)(A + (size_t)(m0 + row) * lda + c);
            } else {
                int cc = (c < 512) ? c : c + 256;
                const short* base = A + (size_t)(m0 + row) * lda + cc;
                bf16x8 x = *(const bf16x8*)(base);
                bf16x8 y = *(const bf16x8*)(base + 256);
                #pragma unroll
                for (int e = 0; e < 8; ++e) av[e] = f2bf(bf2f(x[e]) + bf2f(y[e]));
            }
            *(bf16x8*)&As[row * 64 + ((g ^ (row & 7)) << 3)] = av;
            *(bf16x8*)&Bs[row * 64 + ((g ^ (row & 7)) << 3)] =
                *(const bf16x8*)(Bt + (size_t)(n0 + row) * K + k0 + g * 8);
        }
        __syncthreads();
        #pragma unroll
        for (int ks = 0; ks < 2; ++ks) {
            int arow = w * 16 + lr;
            bf16x8 af = *(const bf16x8*)&As[arow * 64 + (((ks*4 + q) ^ (arow & 7)) << 3)];
            #pragma unroll
            for (int nt = 0; nt < 4; ++nt) {
                int brow = nt * 16 + lr;
                bf16x8 bfg = *(const bf16x8*)&Bs[brow * 64 + (((ks*4 + q) ^ (brow & 7)) << 3)];
                acc[nt] = __builtin_amdgcn_mfma_f32_16x16x32_bf16(af, bfg, acc[nt], 0, 0, 0);
            }
        }
    }
    #pragma unroll
    for (int nt = 0; nt < 4; ++nt)
        #pragma unroll
        for (int r = 0; r < 4; ++r) {
            int m = m0 + w * 16 + q * 4 + r;      // C/D: row = quad*4 + reg
            int n = n0 + nt * 16 + lr;            //      col = lane & 15
            float v = acc[nt][r] + bias[n];
            v = v > 0.f ? v : 0.f;
            if (out_bf16) {
                int col = swz ? ((((n >> 3) ^ (m & 7)) << 3) | (n & 7)) : n;
                ((short*)outp)[(size_t)m * ldo + col] = f2bf(v);
            } else {
                ((float*)outp)[(size_t)m * ldo + n] = v;
            }
        }
}

// ------------------------------------------------------------- e_to_fp8
// bf16 e (16B-chunk swizzled) -> fp8 e4m3 shadow, 8B-granule swizzled:
// granule g of row m lands at slot (g&24)|((g&7)^(m&7)). One thread per 8B.
__global__ void e_to_fp8(const short* __restrict__ e1, const short* __restrict__ e2,
                         char* __restrict__ o1, char* __restrict__ o2)
{
    int gid = blockIdx.x * 256 + threadIdx.x;          // 0 .. 524287
    const short* e = (gid >> 18) ? e2 : e1;
    char*        o = (gid >> 18) ? o2 : o1;
    int rem = gid & 262143;
    int m = rem >> 5, g = rem & 31;
    int slot = (g & 24) | ((g & 7) ^ (m & 7));
    bf16x8 v = *(const bf16x8*)(e + (size_t)m * 256 + slot * 8);
    float f[8];
    #pragma unroll
    for (int i = 0; i < 8; ++i) f[i] = bf2f(v[i]);
    int a = __builtin_amdgcn_cvt_pk_fp8_f32(f[0], f[1], 0, false);
    a     = __builtin_amdgcn_cvt_pk_fp8_f32(f[2], f[3], a, true);
    int b = __builtin_amdgcn_cvt_pk_fp8_f32(f[4], f[5], 0, false);
    b     = __builtin_amdgcn_cvt_pk_fp8_f32(f[6], f[7], b, true);
    int2 r{a, b};
    *(int2*)(o + (size_t)m * 256 + slot * 8) = r;
}

// ---------------------------------------------------------- fused_simagg
// 768 thr: waves 0-3 produce P(jt) (fp8 QK) into Ps[jt&1]; waves 4-11
// consume P(jt-1) with V from Xt (n-strip 32 each, agg=32 AGPRs).
__global__ __launch_bounds__(768, 6)
void fused_simagg(const char* __restrict__ e1f8, const char* __restrict__ e2f8,
                  const short* __restrict__ Xt, short* __restrict__ h,
                  int ldh, int tiles_per_split)
{
    // XCD swizzle: grid (128,2,2) -> each (sim,jz) quadrant on 2 fixed XCDs.
    int sim, jz, mx;
    if (gridDim.x == 128 && gridDim.z == 2) {
        int flat = blockIdx.x + 128 * (blockIdx.y + 2 * blockIdx.z);
        int xcd = flat & 7, slot = flat >> 3;
        int quad = xcd >> 1;
        sim = quad >> 1; jz = quad & 1;
        mx = slot + (xcd & 1) * 64;
    } else { sim = blockIdx.y; jz = blockIdx.z; mx = blockIdx.x; }

    const char* e8 = sim ? e2f8 : e1f8;
    const int m0 = mx * 64;
    const int t = threadIdx.x;
    const int w = t >> 6, l = t & 63, lr = l & 15, q = l >> 4;

    __shared__ __attribute__((aligned(16))) char  Ks8[2][64 * 256]; // 32 KB
    __shared__ __attribute__((aligned(16))) short Ps[2][64 * 64];   // 16 KB

    const int jbase = jz * tiles_per_split;
    const int T = tiles_per_split;

    if (w < 4) {
        // ============ producer: S^T = K.Q^T (fp8) -> Ps (bf16) ============
        const int mh = (w & 1) * 32;           // m-half of this wave
        const int jh = (w >> 1) * 32;          // j-half of this wave
        const int wub = t & ~63;               // wave-uniform base (t 0..255)

        long qf8[2][8];                        // 32 VGPRs: fp8 Q frags
        #pragma unroll
        for (int ms = 0; ms < 2; ++ms) {
            const int mrow = m0 + mh + ms * 16 + lr;
            const char* qrow = e8 + (size_t)mrow * 256;
            #pragma unroll
            for (int kc = 0; kc < 8; ++kc) {
                int g = kc * 4 + q;
                int slot = (g & 24) | ((g & 7) ^ (mrow & 7));
                qf8[ms][kc] = *(const long*)(qrow + slot * 8);
            }
        }
        // prologue: stage tile 0 (16 KB = 1024 granules over 256 threads)
        {
            const char* src = e8 + (size_t)(jbase * 64) * 256;
            #pragma unroll
            for (int it = 0; it < 4; ++it)
                cp16_async(src + (size_t)(it * 256 + t) * 16,
                           &Ks8[0][(size_t)(it * 256 + wub) * 16]);
        }
        __syncthreads();                       // barrier 0 (matches consumer)

        for (int jt = 0; jt <= T; ++jt) {
            if (jt < T) {
                const int cur = jt & 1;
                const int j0 = (jbase + jt) * 64;
                if (jt + 1 < T) {              // async prefetch of next K tile
                    const char* src = e8 + (size_t)(j0 + 64) * 256;
                    #pragma unroll
                    for (int it = 0; it < 4; ++it)
                        cp16_async(src + (size_t)(it * 256 + t) * 16,
                                   &Ks8[cur ^ 1][(size_t)(it * 256 + wub) * 16]);
                }
                const char* Kb = &Ks8[cur][0];
                f32x4 s[2][2];                 // [js2][ms]
                #pragma unroll
                for (int a = 0; a < 2; ++a)
                    #pragma unroll
                    for (int b = 0; b < 2; ++b) s[a][b] = f32x4{0.f, 0.f, 0.f, 0.f};
                #pragma unroll
                for (int kc = 0; kc < 8; ++kc) {
                    #pragma unroll
                    for (int js2 = 0; js2 < 2; ++js2) {
                        int row = jh + js2 * 16 + lr;
                        int g = kc * 4 + q;
                        int slot = (g & 24) | ((g & 7) ^ (row & 7));
                        long kf = *(const long*)&Kb[row * 256 + slot * 8];
                        #pragma unroll
                        for (int ms = 0; ms < 2; ++ms)
                            s[js2][ms] = __builtin_amdgcn_mfma_f32_16x16x32_fp8_fp8(
                                kf, qf8[ms][kc], s[js2][ms], 0, 0, 0);
                    }
                }
                // P scatter: 4 consecutive j at fixed m -> one aligned b64
                #pragma unroll
                for (int js2 = 0; js2 < 2; ++js2)
                    #pragma unroll
                    for (int ms = 0; ms < 2; ++ms) {
                        int mloc = mh + ms * 16 + lr;
                        int jj = jh + js2 * 16 + q * 4;
                        int off = mloc * 64 + (((jj >> 3) ^ (mloc & 7)) << 3) + (jj & 7);
                        short4v pk = { f2bf(s[js2][ms][0] * (1.0f/256.0f)),
                                       f2bf(s[js2][ms][1] * (1.0f/256.0f)),
                                       f2bf(s[js2][ms][2] * (1.0f/256.0f)),
                                       f2bf(s[js2][ms][3] * (1.0f/256.0f)) };
                        *(short4v*)&Ps[cur][off] = pk;
                    }
            }
            __syncthreads();                   // barrier per tile
        }
    } else {
        // ======= consumer: agg += P(jt-1) x V, n-strip 32 per wave =======
        const int wv = w - 4;                  // n-strip selector 0..7
        f32x4 agg[8];                          // 32 AGPRs (4 mt x 2 nt)
        #pragma unroll
        for (int i = 0; i < 8; ++i) agg[i] = f32x4{0.f, 0.f, 0.f, 0.f};

        __syncthreads();                       // barrier 0 (matches producer)

        for (int jt = 0; jt <= T; ++jt) {
            if (jt >= 1) {
                const int p = (jt - 1) & 1;
                const int j0 = (jbase + jt - 1) * 64;
                #pragma unroll
                for (int ks = 0; ks < 2; ++ks) {
                    bf16x8 pf[4], vfr[2];
                    #pragma unroll
                    for (int nt = 0; nt < 2; ++nt) {
                        int n = wv * 32 + nt * 16 + lr;
                        vfr[nt] = *(const bf16x8*)(Xt + (size_t)n * 8192 + j0 + (ks * 4 + q) * 8);
                    }
                    #pragma unroll
                    for (int mt = 0; mt < 4; ++mt) {
                        int row = mt * 16 + lr;
                        pf[mt] = *(const bf16x8*)&Ps[p][row * 64 + (((ks*4 + q) ^ (row & 7)) << 3)];
                    }
                    #pragma unroll
                    for (int nt = 0; nt < 2; ++nt)
                        #pragma unroll
                        for (int mt = 0; mt < 4; ++mt)
                            agg[mt * 2 + nt] = __builtin_amdgcn_mfma_f32_16x16x32_bf16(
                                pf[mt], vfr[nt], agg[mt * 2 + nt], 0, 0, 0);
                }
            }
            __syncthreads();                   // barrier per tile
        }

        const int colbase = 256 + (sim * gridDim.z + jz) * 256;
        #pragma unroll
        for (int mt = 0; mt < 4; ++mt)
            #pragma unroll
            for (int nt = 0; nt < 2; ++nt)
                #pragma unroll
                for (int r = 0; r < 4; ++r) {
                    int m = m0 + mt * 16 + q * 4 + r;
                    int n = wv * 32 + nt * 16 + lr;
                    h[(size_t)m * ldh + colbase + n] = f2bf(agg[mt * 2 + nt][r]);
                }
    }
}

// ---------------------------------------------------------------- launch
extern "C" void kernel_launch(void* const* d_in, const int* in_sizes, int n_in,
                              void* d_out, int out_size, void* d_ws, size_t ws_size,
                              hipStream_t stream)
{
    const float* edge_x = (const float*)d_in[0];
    const float* W1 = (const float*)d_in[1];
    const float* b1 = (const float*)d_in[2];
    const float* W2 = (const float*)d_in[3];
    const float* b2 = (const float*)d_in[4];
    const float* Wo = (const float*)d_in[5];
    const float* bo = (const float*)d_in[6];

    const size_t fixed = 4194304u * 3 + 131072u * 2 + 393216u + 4194304u;
    const size_t need2 = (size_t)8192 * 1280 * 2 + fixed;
    const int js = (ws_size >= need2) ? 2 : 1;
    const int H = 256 + 2 * js * 256;              // 1280 or 768

    char* ws = (char*)d_ws;
    short* h    = (short*)ws;
    short* Xt   = (short*)(ws + (size_t)8192 * H * 2);
    short* e1   = (short*)((char*)Xt + 4194304);
    short* e2   = (short*)((char*)e1 + 4194304);
    short* Wt1  = (short*)((char*)e2 + 4194304);
    short* Wt2  = (short*)((char*)Wt1 + 131072);
    short* Wto  = (short*)((char*)Wt2 + 131072);   // 768 x 256 bf16
    char*  e1f8 = (char*)Wto + 393216;
    char*  e2f8 = e1f8 + 2097152;

    prep_all<<<dim3(256, 8), dim3(32, 8), 0, stream>>>(
        edge_x, h, H, Xt, W1, W2, Wo, Wt1, Wt2, Wto);

    // e1 and e2 GEMMs in one dispatch (grid.z)
    gemm_bias_relu<<<dim3(128, 4, 2), 256, 0, stream>>>(
        h, H, Wt1, Wt2, 256, b1, b2, e1, e2, 1, 256, 1, 0);
    // fp8 shadow of e1/e2
    e_to_fp8<<<dim3(2048), 256, 0, stream>>>(e1, e2, e1f8, e2f8);
    // 64-row j-tiles: (8192/64)/js per split
    fused_simagg<<<dim3(128, 2, js), 768, 0, stream>>>(e1f8, e2f8, Xt, h, H, 128 / js);
    // final GEMM: K=768 with partial-pair reduction during staging (js==2)
    gemm_bias_relu<<<dim3(128, 4, 1), 256, 0, stream>>>(
        h, H, Wto, Wto, 768, bo, bo, (float*)d_out, (float*)d_out, 0, 256, 0, js == 2);
}

// Round 11
// 241.739 us; speedup vs baseline: 1.0783x; 1.0783x over previous
//
#include <hip/hip_runtime.h>
#include <hip/hip_bf16.h>

// MPNN fused pipeline. R11 = R9 fused (proven 154us: 4 prod + 4 cons waves,
// 512thr, n-strip 64) + aux-path cuts:
//  - R10's 8-consumer split REVERTED: every consumer reads all of Ps, so
//    halving the n-strip doubled pf LDS traffic (R10: LDS 2.3k->3.0k
//    cyc/period, wall 5.7k->6.3k). Waves that multiply LDS reads lose.
//  - e-GEMM epilogue now emits the fp8 granule-swizzled shadow DIRECTLY
//    (acc -> As LDS restage -> pack 8B granules). bf16 e1/e2 arrays and the
//    e_to_fp8 kernel are deleted (-1 launch, -20MB of traffic).
//  - final GEMM keeps the pairadd partial reduction (K=768).

typedef short bf16x8  __attribute__((ext_vector_type(8)));
typedef short short4v __attribute__((ext_vector_type(4)));
typedef float f32x4   __attribute__((ext_vector_type(4)));

__device__ inline short f2bf(float x) {                // fp32 -> bf16 RNE
    unsigned u = __builtin_bit_cast(unsigned, x);
    return (short)((u + 0x7fffu + ((u >> 16) & 1u)) >> 16);
}
__device__ inline float bf2f(short b) {
    return __builtin_bit_cast(float, (unsigned)((unsigned short)b) << 16);
}
__device__ inline void cp16_async(const char* g, char* l) {
    __builtin_amdgcn_global_load_lds(
        (const __attribute__((address_space(1))) unsigned int*)g,
        (__attribute__((address_space(3))) unsigned int*)l, 16, 0, 0);
}

// ------------------------------------------------------------------ prep_all
// All blocks: edge_x fp32 -> bf16 h[:,0:256] + Xt [256][8192].
// Blocks (x<8,y<8) additionally loop the 5 weight transposes (Wto ld=768).
__global__ void prep_all(const float* __restrict__ X, short* __restrict__ h,
                         int ldh, short* __restrict__ Xt,
                         const float* __restrict__ W1, const float* __restrict__ W2,
                         const float* __restrict__ Wo,
                         short* __restrict__ Wt1, short* __restrict__ Wt2,
                         short* __restrict__ Wto)
{
    __shared__ short tile[32][33];
    const int tx = threadIdx.x, ty = threadIdx.y;      // 32 x 8
    {
        const int r0 = blockIdx.x * 32, c0 = blockIdx.y * 32;
        #pragma unroll
        for (int i = 0; i < 4; ++i) {
            int row = ty + i * 8;
            short b = f2bf(X[(size_t)(r0 + row) * 256 + c0 + tx]);
            tile[row][tx] = b;
            h[(size_t)(r0 + row) * ldh + c0 + tx] = b;
        }
        __syncthreads();
        #pragma unroll
        for (int i = 0; i < 4; ++i) {
            int row = ty + i * 8;
            Xt[(size_t)(c0 + row) * 8192 + r0 + tx] = tile[tx][row];
        }
    }
    if (blockIdx.x < 8 && blockIdx.y < 8) {
        const int k0 = blockIdx.x * 32, n0 = blockIdx.y * 32;
        for (int z = 0; z < 5; ++z) {
            const float* src; short* dst; int ldwt, k_off;
            if (z == 0)      { src = W1; dst = Wt1; ldwt = 256; k_off = 0; }
            else if (z == 1) { src = W2; dst = Wt2; ldwt = 256; k_off = 0; }
            else {
                int g = z - 2;                  // 0..2 -> Wo rows g*256
                src = Wo + (size_t)g * 256 * 256; dst = Wto; ldwt = 768; k_off = g * 256;
            }
            __syncthreads();
            #pragma unroll
            for (int i = 0; i < 4; ++i) {
                int row = ty + i * 8;
                tile[row][tx] = f2bf(src[(size_t)(k0 + row) * 256 + n0 + tx]);
            }
            __syncthreads();
            #pragma unroll
            for (int i = 0; i < 4; ++i) {
                int row = ty + i * 8;
                dst[(size_t)(n0 + row) * ldwt + k_off + k0 + tx] = tile[tx][row];
            }
        }
    }
}

// -------------------------------------------------------- gemm_bias_relu
// out_mode: 0 = fp32 plain store; 2 = fp8-e4m3 granule-swizzled shadow
// (granule g of row m lands at slot (g&24)|((g&7)^(m&7)), matching the
// fused producer's DMA/frag layout).
// pairadd: A col c (c>=256) = h[cc] + h[cc+256], cc = c + (c<512 ? 0 : 256).
__global__ __launch_bounds__(256, 1)
void gemm_bias_relu(const short* __restrict__ A, int lda,
                    const short* __restrict__ Bt0, const short* __restrict__ Bt1,
                    int K,
                    const float* __restrict__ bias0, const float* __restrict__ bias1,
                    void* __restrict__ out0, void* __restrict__ out1,
                    int out_mode, int ldo, int pairadd)
{
    const short* Bt   = blockIdx.z ? Bt1   : Bt0;
    const float* bias = blockIdx.z ? bias1 : bias0;
    void*        outp = blockIdx.z ? out1  : out0;

    const int m0 = blockIdx.x * 64, n0 = blockIdx.y * 64;
    const int t = threadIdx.x;
    const int w = t >> 6, l = t & 63, lr = l & 15, q = l >> 4;

    __shared__ __attribute__((aligned(16))) short As[64 * 64];
    __shared__ __attribute__((aligned(16))) short Bs[64 * 64];

    f32x4 acc[4];
    #pragma unroll
    for (int i = 0; i < 4; ++i) acc[i] = f32x4{0.f, 0.f, 0.f, 0.f};

    for (int k0 = 0; k0 < K; k0 += 64) {
        __syncthreads();
        for (int i = t; i < 64 * 8; i += 256) {
            int row = i >> 3, g = i & 7;
            int c = k0 + g * 8;
            bf16x8 av;
            if (!pairadd || c < 256) {
                av = *(const bf16x8*)(A + (size_t)(m0 + row) * lda + c);
            } else {
                int cc = (c < 512) ? c : c + 256;
                const short* base = A + (size_t)(m0 + row) * lda + cc;
                bf16x8 x = *(const bf16x8*)(base);
                bf16x8 y = *(const bf16x8*)(base + 256);
                #pragma unroll
                for (int e = 0; e < 8; ++e) av[e] = f2bf(bf2f(x[e]) + bf2f(y[e]));
            }
            *(bf16x8*)&As[row * 64 + ((g ^ (row & 7)) << 3)] = av;
            *(bf16x8*)&Bs[row * 64 + ((g ^ (row & 7)) << 3)] =
                *(const bf16x8*)(Bt + (size_t)(n0 + row) * K + k0 + g * 8);
        }
        __syncthreads();
        #pragma unroll
        for (int ks = 0; ks < 2; ++ks) {
            int arow = w * 16 + lr;
            bf16x8 af = *(const bf16x8*)&As[arow * 64 + (((ks*4 + q) ^ (arow & 7)) << 3)];
            #pragma unroll
            for (int nt = 0; nt < 4; ++nt) {
                int brow = nt * 16 + lr;
                bf16x8 bfg = *(const bf16x8*)&Bs[brow * 64 + (((ks*4 + q) ^ (brow & 7)) << 3)];
                acc[nt] = __builtin_amdgcn_mfma_f32_16x16x32_bf16(af, bfg, acc[nt], 0, 0, 0);
            }
        }
    }

    if (out_mode == 0) {
        #pragma unroll
        for (int nt = 0; nt < 4; ++nt)
            #pragma unroll
            for (int r = 0; r < 4; ++r) {
                int m = m0 + w * 16 + q * 4 + r;  // C/D: row = quad*4 + reg
                int n = n0 + nt * 16 + lr;        //      col = lane & 15
                float v = acc[nt][r] + bias[n];
                ((float*)outp)[(size_t)m * ldo + n] = v > 0.f ? v : 0.f;
            }
    } else {
        // fp8 epilogue: restage relu(acc+bias) as bf16 in As (unswizzled),
        // then pack 8-value granules into the swizzled global shadow.
        __syncthreads();                          // As K-loop readers done
        #pragma unroll
        for (int nt = 0; nt < 4; ++nt)
            #pragma unroll
            for (int r = 0; r < 4; ++r) {
                int mloc = w * 16 + q * 4 + r;
                int nloc = nt * 16 + lr;
                float v = acc[nt][r] + bias[n0 + nloc];
                As[mloc * 64 + nloc] = f2bf(v > 0.f ? v : 0.f);
            }
        __syncthreads();
        char* o = (char*)outp;
        for (int i = t; i < 512; i += 256) {      // 64 rows x 8 granules
            int rloc = i >> 3, g = i & 7;
            bf16x8 vv = *(const bf16x8*)&As[rloc * 64 + g * 8];
            float f[8];
            #pragma unroll
            for (int e = 0; e < 8; ++e) f[e] = bf2f(vv[e]);
            int a = __builtin_amdgcn_cvt_pk_fp8_f32(f[0], f[1], 0, false);
            a     = __builtin_amdgcn_cvt_pk_fp8_f32(f[2], f[3], a, true);
            int b = __builtin_amdgcn_cvt_pk_fp8_f32(f[4], f[5], 0, false);
            b     = __builtin_amdgcn_cvt_pk_fp8_f32(f[6], f[7], b, true);
            int m = m0 + rloc;
            int gg = (n0 >> 3) + g;
            int slot = (gg & 24) | ((gg & 7) ^ (m & 7));
            int2 r2{a, b};
            *(int2*)(o + (size_t)m * 256 + slot * 8) = r2;
        }
    }
}

// ---------------------------------------------------------- fused_simagg
// R9-proven config: 512 thr, waves 0-3 produce P(jt) (fp8 QK) into
// Ps[jt&1]; waves 4-7 consume P(jt-1) with V from Xt. 1 barrier/tile.
__global__ __launch_bounds__(512, 4)
void fused_simagg(const char* __restrict__ e1f8, const char* __restrict__ e2f8,
                  const short* __restrict__ Xt, short* __restrict__ h,
                  int ldh, int tiles_per_split)
{
    // XCD swizzle: grid (128,2,2) -> each (sim,jz) quadrant on 2 fixed XCDs.
    int sim, jz, mx;
    if (gridDim.x == 128 && gridDim.z == 2) {
        int flat = blockIdx.x + 128 * (blockIdx.y + 2 * blockIdx.z);
        int xcd = flat & 7, slot = flat >> 3;
        int quad = xcd >> 1;
        sim = quad >> 1; jz = quad & 1;
        mx = slot + (xcd & 1) * 64;
    } else { sim = blockIdx.y; jz = blockIdx.z; mx = blockIdx.x; }

    const char* e8 = sim ? e2f8 : e1f8;
    const int m0 = mx * 64;
    const int t = threadIdx.x;
    const int w = t >> 6, l = t & 63, lr = l & 15, q = l >> 4;

    __shared__ __attribute__((aligned(16))) char  Ks8[2][64 * 256]; // 32 KB
    __shared__ __attribute__((aligned(16))) short Ps[2][64 * 64];   // 16 KB

    const int jbase = jz * tiles_per_split;
    const int T = tiles_per_split;

    if (w < 4) {
        // ============ producer: S^T = K.Q^T (fp8) -> Ps (bf16) ============
        const int mh = (w & 1) * 32;           // m-half of this wave
        const int jh = (w >> 1) * 32;          // j-half of this wave
        const int wub = t & ~63;               // wave-uniform base (t 0..255)

        long qf8[2][8];                        // 32 VGPRs: fp8 Q frags
        #pragma unroll
        for (int ms = 0; ms < 2; ++ms) {
            const int mrow = m0 + mh + ms * 16 + lr;
            const char* qrow = e8 + (size_t)mrow * 256;
            #pragma unroll
            for (int kc = 0; kc < 8; ++kc) {
                int g = kc * 4 + q;
                int slot = (g & 24) | ((g & 7) ^ (mrow & 7));
                qf8[ms][kc] = *(const long*)(qrow + slot * 8);
            }
        }
        // prologue: stage tile 0 (16 KB = 1024 granules over 256 threads)
        {
            const char* src = e8 + (size_t)(jbase * 64) * 256;
            #pragma unroll
            for (int it = 0; it < 4; ++it)
                cp16_async(src + (size_t)(it * 256 + t) * 16,
                           &Ks8[0][(size_t)(it * 256 + wub) * 16]);
        }
        __syncthreads();                       // barrier 0 (matches consumer)

        for (int jt = 0; jt <= T; ++jt) {
            if (jt < T) {
                const int cur = jt & 1;
                const int j0 = (jbase + jt) * 64;
                if (jt + 1 < T) {              // async prefetch of next K tile
                    const char* src = e8 + (size_t)(j0 + 64) * 256;
                    #pragma unroll
                    for (int it = 0; it < 4; ++it)
                        cp16_async(src + (size_t)(it * 256 + t) * 16,
                                   &Ks8[cur ^ 1][(size_t)(it * 256 + wub) * 16]);
                }
                const char* Kb = &Ks8[cur][0];
                f32x4 s[2][2];                 // [js2][ms]
                #pragma unroll
                for (int a = 0; a < 2; ++a)
                    #pragma unroll
                    for (int b = 0; b < 2; ++b) s[a][b] = f32x4{0.f, 0.f, 0.f, 0.f};
                #pragma unroll
                for (int kc = 0; kc < 8; ++kc) {
                    #pragma unroll
                    for (int js2 = 0; js2 < 2; ++js2) {
                        int row = jh + js2 * 16 + lr;
                        int g = kc * 4 + q;
                        int slot = (g & 24) | ((g & 7) ^ (row & 7));
                        long kf = *(const long*)&Kb[row * 256 + slot * 8];
                        #pragma unroll
                        for (int ms = 0; ms < 2; ++ms)
                            s[js2][ms] = __builtin_amdgcn_mfma_f32_16x16x32_fp8_fp8(
                                kf, qf8[ms][kc], s[js2][ms], 0, 0, 0);
                    }
                }
                // P scatter: 4 consecutive j at fixed m -> one aligned b64
                #pragma unroll
                for (int js2 = 0; js2 < 2; ++js2)
                    #pragma unroll
                    for (int ms = 0; ms < 2; ++ms) {
                        int mloc = mh + ms * 16 + lr;
                        int jj = jh + js2 * 16 + q * 4;
                        int off = mloc * 64 + (((jj >> 3) ^ (mloc & 7)) << 3) + (jj & 7);
                        short4v pk = { f2bf(s[js2][ms][0] * (1.0f/256.0f)),
                                       f2bf(s[js2][ms][1] * (1.0f/256.0f)),
                                       f2bf(s[js2][ms][2] * (1.0f/256.0f)),
                                       f2bf(s[js2][ms][3] * (1.0f/256.0f)) };
                        *(short4v*)&Ps[cur][off] = pk;
                    }
            }
            __syncthreads();                   // barrier per tile
        }
    } else {
        // ============ consumer: agg += P(jt-1) x V (R9 config) ============
        const int wv = w - 4;                  // n-strip selector 0..3
        f32x4 agg[16];                         // 64 AGPRs
        #pragma unroll
        for (int i = 0; i < 16; ++i) agg[i] = f32x4{0.f, 0.f, 0.f, 0.f};

        __syncthreads();                       // barrier 0 (matches producer)

        for (int jt = 0; jt <= T; ++jt) {
            if (jt >= 1) {
                const int p = (jt - 1) & 1;
                const int j0 = (jbase + jt - 1) * 64;
                #pragma unroll
                for (int ks = 0; ks < 2; ++ks) {
                    bf16x8 pf[4], vfr[4];
                    #pragma unroll
                    for (int nt = 0; nt < 4; ++nt) {
                        int n = wv * 64 + nt * 16 + lr;
                        vfr[nt] = *(const bf16x8*)(Xt + (size_t)n * 8192 + j0 + (ks * 4 + q) * 8);
                    }
                    #pragma unroll
                    for (int mt = 0; mt < 4; ++mt) {
                        int row = mt * 16 + lr;
                        pf[mt] = *(const bf16x8*)&Ps[p][row * 64 + (((ks*4 + q) ^ (row & 7)) << 3)];
                    }
                    #pragma unroll
                    for (int nt = 0; nt < 4; ++nt)
                        #pragma unroll
                        for (int mt = 0; mt < 4; ++mt)
                            agg[mt * 4 + nt] = __builtin_amdgcn_mfma_f32_16x16x32_bf16(
                                pf[mt], vfr[nt], agg[mt * 4 + nt], 0, 0, 0);
                }
            }
            __syncthreads();                   // barrier per tile
        }

        const int colbase = 256 + (sim * gridDim.z + jz) * 256;
        #pragma unroll
        for (int mt = 0; mt < 4; ++mt)
            #pragma unroll
            for (int nt = 0; nt < 4; ++nt)
                #pragma unroll
                for (int r = 0; r < 4; ++r) {
                    int m = m0 + mt * 16 + q * 4 + r;
                    int n = wv * 64 + nt * 16 + lr;
                    h[(size_t)m * ldh + colbase + n] = f2bf(agg[mt * 4 + nt][r]);
                }
    }
}

// ---------------------------------------------------------------- launch
extern "C" void kernel_launch(void* const* d_in, const int* in_sizes, int n_in,
                              void* d_out, int out_size, void* d_ws, size_t ws_size,
                              hipStream_t stream)
{
    const float* edge_x = (const float*)d_in[0];
    const float* W1 = (const float*)d_in[1];
    const float* b1 = (const float*)d_in[2];
    const float* W2 = (const float*)d_in[3];
    const float* b2 = (const float*)d_in[4];
    const float* Wo = (const float*)d_in[5];
    const float* bo = (const float*)d_in[6];

    const size_t fixed = 4194304u + 131072u * 2 + 393216u + 2097152u * 2; // Xt+Wt12+Wto+e8s
    const size_t need2 = (size_t)8192 * 1280 * 2 + fixed;
    const int js = (ws_size >= need2) ? 2 : 1;
    const int H = 256 + 2 * js * 256;              // 1280 or 768

    char* ws = (char*)d_ws;
    short* h    = (short*)ws;
    short* Xt   = (short*)(ws + (size_t)8192 * H * 2);
    short* Wt1  = (short*)((char*)Xt + 4194304);
    short* Wt2  = (short*)((char*)Wt1 + 131072);
    short* Wto  = (short*)((char*)Wt2 + 131072);   // 768 x 256 bf16
    char*  e1f8 = (char*)Wto + 393216;
    char*  e2f8 = e1f8 + 2097152;

    prep_all<<<dim3(256, 8), dim3(32, 8), 0, stream>>>(
        edge_x, h, H, Xt, W1, W2, Wo, Wt1, Wt2, Wto);

    // e1/e2 GEMMs -> fp8 shadows directly (one dispatch, grid.z)
    gemm_bias_relu<<<dim3(128, 4, 2), 256, 0, stream>>>(
        h, H, Wt1, Wt2, 256, b1, b2, e1f8, e2f8, 2, 256, 0);
    // 64-row j-tiles: (8192/64)/js per split
    fused_simagg<<<dim3(128, 2, js), 512, 0, stream>>>(e1f8, e2f8, Xt, h, H, 128 / js);
    // final GEMM: K=768 with partial-pair reduction during staging (js==2)
    gemm_bias_relu<<<dim3(128, 4, 1), 256, 0, stream>>>(
        h, H, Wto, Wto, 768, bo, bo, (float*)d_out, (float*)d_out, 0, 256, js == 2);
}

// Round 12
// 236.844 us; speedup vs baseline: 1.1006x; 1.0207x over previous
//
#include <hip/hip_runtime.h>
#include <hip/hip_bf16.h>

// MPNN fused pipeline. R12 = R11 + prep_all weight-tile parallelization.
// R11 recap: fused_simagg = producer/consumer wave specialization (4 fp8-QK
// producer waves + 4 bf16-PV consumer waves, 512thr, Ps dbuf, 1 barrier per
// 64-row j-tile, fp8 shadow consumed directly from the e-GEMM epilogue).
// Fused is latency-pinned at 2 blocks/CU: consumer = 64 AGPR + 64 VGPR =
// exactly the 128-reg / 4-waves-per-SIMD bracket; all deeper pipelining is
// defeated by the vmcnt(0) drain at __syncthreads (R5/R7/R10 evidence).
// R12 change: prep_all's 64 blocks serialized FIVE weight-tile transposes
// (the dispatch tail). Now all 320 weight tiles get their own parallel
// blocks (grid y in {8,9}, one tile + one barrier each).

typedef short bf16x8  __attribute__((ext_vector_type(8)));
typedef short short4v __attribute__((ext_vector_type(4)));
typedef float f32x4   __attribute__((ext_vector_type(4)));

__device__ inline short f2bf(float x) {                // fp32 -> bf16 RNE
    unsigned u = __builtin_bit_cast(unsigned, x);
    return (short)((u + 0x7fffu + ((u >> 16) & 1u)) >> 16);
}
__device__ inline float bf2f(short b) {
    return __builtin_bit_cast(float, (unsigned)((unsigned short)b) << 16);
}
__device__ inline void cp16_async(const char* g, char* l) {
    __builtin_amdgcn_global_load_lds(
        (const __attribute__((address_space(1))) unsigned int*)g,
        (__attribute__((address_space(3))) unsigned int*)l, 16, 0, 0);
}

// ------------------------------------------------------------------ prep_all
// grid (256,10), block (32,8):
//   y<8 : edge_x fp32 -> bf16 h[:,0:256] + Xt [256][8192] (one 32x32 tile)
//   y>=8: weight tile (base = (y-8)*256 + x, 320 tiles total):
//         0-63 W1->Wt1, 64-127 W2->Wt2, 128-319 Wo group g -> Wto k-block g.
__global__ void prep_all(const float* __restrict__ X, short* __restrict__ h,
                         int ldh, short* __restrict__ Xt,
                         const float* __restrict__ W1, const float* __restrict__ W2,
                         const float* __restrict__ Wo,
                         short* __restrict__ Wt1, short* __restrict__ Wt2,
                         short* __restrict__ Wto)
{
    __shared__ short tile[32][33];
    const int tx = threadIdx.x, ty = threadIdx.y;      // 32 x 8
    if (blockIdx.y < 8) {
        const int r0 = blockIdx.x * 32, c0 = blockIdx.y * 32;
        #pragma unroll
        for (int i = 0; i < 4; ++i) {
            int row = ty + i * 8;
            short b = f2bf(X[(size_t)(r0 + row) * 256 + c0 + tx]);
            tile[row][tx] = b;
            h[(size_t)(r0 + row) * ldh + c0 + tx] = b;
        }
        __syncthreads();
        #pragma unroll
        for (int i = 0; i < 4; ++i) {
            int row = ty + i * 8;
            Xt[(size_t)(c0 + row) * 8192 + r0 + tx] = tile[tx][row];
        }
    } else {
        int tw = (blockIdx.y - 8) * 256 + blockIdx.x;
        if (tw >= 320) return;
        const float* src; short* dst; int ldwt, k_off, kx, ny;
        if (tw < 64)       { src = W1; dst = Wt1; ldwt = 256; k_off = 0;
                             kx = tw >> 3; ny = tw & 7; }
        else if (tw < 128) { int u = tw - 64; src = W2; dst = Wt2; ldwt = 256;
                             k_off = 0; kx = u >> 3; ny = u & 7; }
        else               { int u = tw - 128; int g = u >> 6; int rem = u & 63;
                             src = Wo + (size_t)g * 256 * 256; dst = Wto;
                             ldwt = 768; k_off = g * 256;
                             kx = rem >> 3; ny = rem & 7; }
        const int k0 = kx * 32, n0 = ny * 32;
        #pragma unroll
        for (int i = 0; i < 4; ++i) {
            int row = ty + i * 8;
            tile[row][tx] = f2bf(src[(size_t)(k0 + row) * 256 + n0 + tx]);
        }
        __syncthreads();
        #pragma unroll
        for (int i = 0; i < 4; ++i) {
            int row = ty + i * 8;
            dst[(size_t)(n0 + row) * ldwt + k_off + k0 + tx] = tile[tx][row];
        }
    }
}

// -------------------------------------------------------- gemm_bias_relu
// out_mode: 0 = fp32 plain store; 2 = fp8-e4m3 granule-swizzled shadow
// (granule g of row m lands at slot (g&24)|((g&7)^(m&7)), matching the
// fused producer's DMA/frag layout).
// pairadd: A col c (c>=256) = h[cc] + h[cc+256], cc = c + (c<512 ? 0 : 256).
__global__ __launch_bounds__(256, 1)
void gemm_bias_relu(const short* __restrict__ A, int lda,
                    const short* __restrict__ Bt0, const short* __restrict__ Bt1,
                    int K,
                    const float* __restrict__ bias0, const float* __restrict__ bias1,
                    void* __restrict__ out0, void* __restrict__ out1,
                    int out_mode, int ldo, int pairadd)
{
    const short* Bt   = blockIdx.z ? Bt1   : Bt0;
    const float* bias = blockIdx.z ? bias1 : bias0;
    void*        outp = blockIdx.z ? out1  : out0;

    const int m0 = blockIdx.x * 64, n0 = blockIdx.y * 64;
    const int t = threadIdx.x;
    const int w = t >> 6, l = t & 63, lr = l & 15, q = l >> 4;

    __shared__ __attribute__((aligned(16))) short As[64 * 64];
    __shared__ __attribute__((aligned(16))) short Bs[64 * 64];

    f32x4 acc[4];
    #pragma unroll
    for (int i = 0; i < 4; ++i) acc[i] = f32x4{0.f, 0.f, 0.f, 0.f};

    for (int k0 = 0; k0 < K; k0 += 64) {
        __syncthreads();
        for (int i = t; i < 64 * 8; i += 256) {
            int row = i >> 3, g = i & 7;
            int c = k0 + g * 8;
            bf16x8 av;
            if (!pairadd || c < 256) {
                av = *(const bf16x8*)(A + (size_t)(m0 + row) * lda + c);
            } else {
                int cc = (c < 512) ? c : c + 256;
                const short* base = A + (size_t)(m0 + row) * lda + cc;
                bf16x8 x = *(const bf16x8*)(base);
                bf16x8 y = *(const bf16x8*)(base + 256);
                #pragma unroll
                for (int e = 0; e < 8; ++e) av[e] = f2bf(bf2f(x[e]) + bf2f(y[e]));
            }
            *(bf16x8*)&As[row * 64 + ((g ^ (row & 7)) << 3)] = av;
            *(bf16x8*)&Bs[row * 64 + ((g ^ (row & 7)) << 3)] =
                *(const bf16x8*)(Bt + (size_t)(n0 + row) * K + k0 + g * 8);
        }
        __syncthreads();
        #pragma unroll
        for (int ks = 0; ks < 2; ++ks) {
            int arow = w * 16 + lr;
            bf16x8 af = *(const bf16x8*)&As[arow * 64 + (((ks*4 + q) ^ (arow & 7)) << 3)];
            #pragma unroll
            for (int nt = 0; nt < 4; ++nt) {
                int brow = nt * 16 + lr;
                bf16x8 bfg = *(const bf16x8*)&Bs[brow * 64 + (((ks*4 + q) ^ (brow & 7)) << 3)];
                acc[nt] = __builtin_amdgcn_mfma_f32_16x16x32_bf16(af, bfg, acc[nt], 0, 0, 0);
            }
        }
    }

    if (out_mode == 0) {
        #pragma unroll
        for (int nt = 0; nt < 4; ++nt)
            #pragma unroll
            for (int r = 0; r < 4; ++r) {
                int m = m0 + w * 16 + q * 4 + r;  // C/D: row = quad*4 + reg
                int n = n0 + nt * 16 + lr;        //      col = lane & 15
                float v = acc[nt][r] + bias[n];
                ((float*)outp)[(size_t)m * ldo + n] = v > 0.f ? v : 0.f;
            }
    } else {
        // fp8 epilogue: restage relu(acc+bias) as bf16 in As (unswizzled),
        // then pack 8-value granules into the swizzled global shadow.
        __syncthreads();                          // As K-loop readers done
        #pragma unroll
        for (int nt = 0; nt < 4; ++nt)
            #pragma unroll
            for (int r = 0; r < 4; ++r) {
                int mloc = w * 16 + q * 4 + r;
                int nloc = nt * 16 + lr;
                float v = acc[nt][r] + bias[n0 + nloc];
                As[mloc * 64 + nloc] = f2bf(v > 0.f ? v : 0.f);
            }
        __syncthreads();
        char* o = (char*)outp;
        for (int i = t; i < 512; i += 256) {      // 64 rows x 8 granules
            int rloc = i >> 3, g = i & 7;
            bf16x8 vv = *(const bf16x8*)&As[rloc * 64 + g * 8];
            float f[8];
            #pragma unroll
            for (int e = 0; e < 8; ++e) f[e] = bf2f(vv[e]);
            int a = __builtin_amdgcn_cvt_pk_fp8_f32(f[0], f[1], 0, false);
            a     = __builtin_amdgcn_cvt_pk_fp8_f32(f[2], f[3], a, true);
            int b = __builtin_amdgcn_cvt_pk_fp8_f32(f[4], f[5], 0, false);
            b     = __builtin_amdgcn_cvt_pk_fp8_f32(f[6], f[7], b, true);
            int m = m0 + rloc;
            int gg = (n0 >> 3) + g;
            int slot = (gg & 24) | ((gg & 7) ^ (m & 7));
            int2 r2{a, b};
            *(int2*)(o + (size_t)m * 256 + slot * 8) = r2;
        }
    }
}

// ---------------------------------------------------------- fused_simagg
// R9-proven config: 512 thr, waves 0-3 produce P(jt) (fp8 QK) into
// Ps[jt&1]; waves 4-7 consume P(jt-1) with V from Xt. 1 barrier/tile.
__global__ __launch_bounds__(512, 4)
void fused_simagg(const char* __restrict__ e1f8, const char* __restrict__ e2f8,
                  const short* __restrict__ Xt, short* __restrict__ h,
                  int ldh, int tiles_per_split)
{
    // XCD swizzle: grid (128,2,2) -> each (sim,jz) quadrant on 2 fixed XCDs.
    int sim, jz, mx;
    if (gridDim.x == 128 && gridDim.z == 2) {
        int flat = blockIdx.x + 128 * (blockIdx.y + 2 * blockIdx.z);
        int xcd = flat & 7, slot = flat >> 3;
        int quad = xcd >> 1;
        sim = quad >> 1; jz = quad & 1;
        mx = slot + (xcd & 1) * 64;
    } else { sim = blockIdx.y; jz = blockIdx.z; mx = blockIdx.x; }

    const char* e8 = sim ? e2f8 : e1f8;
    const int m0 = mx * 64;
    const int t = threadIdx.x;
    const int w = t >> 6, l = t & 63, lr = l & 15, q = l >> 4;

    __shared__ __attribute__((aligned(16))) char  Ks8[2][64 * 256]; // 32 KB
    __shared__ __attribute__((aligned(16))) short Ps[2][64 * 64];   // 16 KB

    const int jbase = jz * tiles_per_split;
    const int T = tiles_per_split;

    if (w < 4) {
        // ============ producer: S^T = K.Q^T (fp8) -> Ps (bf16) ============
        const int mh = (w & 1) * 32;           // m-half of this wave
        const int jh = (w >> 1) * 32;          // j-half of this wave
        const int wub = t & ~63;               // wave-uniform base (t 0..255)

        long qf8[2][8];                        // 32 VGPRs: fp8 Q frags
        #pragma unroll
        for (int ms = 0; ms < 2; ++ms) {
            const int mrow = m0 + mh + ms * 16 + lr;
            const char* qrow = e8 + (size_t)mrow * 256;
            #pragma unroll
            for (int kc = 0; kc < 8; ++kc) {
                int g = kc * 4 + q;
                int slot = (g & 24) | ((g & 7) ^ (mrow & 7));
                qf8[ms][kc] = *(const long*)(qrow + slot * 8);
            }
        }
        // prologue: stage tile 0 (16 KB = 1024 granules over 256 threads)
        {
            const char* src = e8 + (size_t)(jbase * 64) * 256;
            #pragma unroll
            for (int it = 0; it < 4; ++it)
                cp16_async(src + (size_t)(it * 256 + t) * 16,
                           &Ks8[0][(size_t)(it * 256 + wub) * 16]);
        }
        __syncthreads();                       // barrier 0 (matches consumer)

        for (int jt = 0; jt <= T; ++jt) {
            if (jt < T) {
                const int cur = jt & 1;
                const int j0 = (jbase + jt) * 64;
                if (jt + 1 < T) {              // async prefetch of next K tile
                    const char* src = e8 + (size_t)(j0 + 64) * 256;
                    #pragma unroll
                    for (int it = 0; it < 4; ++it)
                        cp16_async(src + (size_t)(it * 256 + t) * 16,
                                   &Ks8[cur ^ 1][(size_t)(it * 256 + wub) * 16]);
                }
                const char* Kb = &Ks8[cur][0];
                f32x4 s[2][2];                 // [js2][ms]
                #pragma unroll
                for (int a = 0; a < 2; ++a)
                    #pragma unroll
                    for (int b = 0; b < 2; ++b) s[a][b] = f32x4{0.f, 0.f, 0.f, 0.f};
                #pragma unroll
                for (int kc = 0; kc < 8; ++kc) {
                    #pragma unroll
                    for (int js2 = 0; js2 < 2; ++js2) {
                        int row = jh + js2 * 16 + lr;
                        int g = kc * 4 + q;
                        int slot = (g & 24) | ((g & 7) ^ (row & 7));
                        long kf = *(const long*)&Kb[row * 256 + slot * 8];
                        #pragma unroll
                        for (int ms = 0; ms < 2; ++ms)
                            s[js2][ms] = __builtin_amdgcn_mfma_f32_16x16x32_fp8_fp8(
                                kf, qf8[ms][kc], s[js2][ms], 0, 0, 0);
                    }
                }
                // P scatter: 4 consecutive j at fixed m -> one aligned b64
                #pragma unroll
                for (int js2 = 0; js2 < 2; ++js2)
                    #pragma unroll
                    for (int ms = 0; ms < 2; ++ms) {
                        int mloc = mh + ms * 16 + lr;
                        int jj = jh + js2 * 16 + q * 4;
                        int off = mloc * 64 + (((jj >> 3) ^ (mloc & 7)) << 3) + (jj & 7);
                        short4v pk = { f2bf(s[js2][ms][0] * (1.0f/256.0f)),
                                       f2bf(s[js2][ms][1] * (1.0f/256.0f)),
                                       f2bf(s[js2][ms][2] * (1.0f/256.0f)),
                                       f2bf(s[js2][ms][3] * (1.0f/256.0f)) };
                        *(short4v*)&Ps[cur][off] = pk;
                    }
            }
            __syncthreads();                   // barrier per tile
        }
    } else {
        // ============ consumer: agg += P(jt-1) x V (R9 config) ============
        const int wv = w - 4;                  // n-strip selector 0..3
        f32x4 agg[16];                         // 64 AGPRs
        #pragma unroll
        for (int i = 0; i < 16; ++i) agg[i] = f32x4{0.f, 0.f, 0.f, 0.f};

        __syncthreads();                       // barrier 0 (matches producer)

        for (int jt = 0; jt <= T; ++jt) {
            if (jt >= 1) {
                const int p = (jt - 1) & 1;
                const int j0 = (jbase + jt - 1) * 64;
                #pragma unroll
                for (int ks = 0; ks < 2; ++ks) {
                    bf16x8 pf[4], vfr[4];
                    #pragma unroll
                    for (int nt = 0; nt < 4; ++nt) {
                        int n = wv * 64 + nt * 16 + lr;
                        vfr[nt] = *(const bf16x8*)(Xt + (size_t)n * 8192 + j0 + (ks * 4 + q) * 8);
                    }
                    #pragma unroll
                    for (int mt = 0; mt < 4; ++mt) {
                        int row = mt * 16 + lr;
                        pf[mt] = *(const bf16x8*)&Ps[p][row * 64 + (((ks*4 + q) ^ (row & 7)) << 3)];
                    }
                    #pragma unroll
                    for (int nt = 0; nt < 4; ++nt)
                        #pragma unroll
                        for (int mt = 0; mt < 4; ++mt)
                            agg[mt * 4 + nt] = __builtin_amdgcn_mfma_f32_16x16x32_bf16(
                                pf[mt], vfr[nt], agg[mt * 4 + nt], 0, 0, 0);
                }
            }
            __syncthreads();                   // barrier per tile
        }

        const int colbase = 256 + (sim * gridDim.z + jz) * 256;
        #pragma unroll
        for (int mt = 0; mt < 4; ++mt)
            #pragma unroll
            for (int nt = 0; nt < 4; ++nt)
                #pragma unroll
                for (int r = 0; r < 4; ++r) {
                    int m = m0 + mt * 16 + q * 4 + r;
                    int n = wv * 64 + nt * 16 + lr;
                    h[(size_t)m * ldh + colbase + n] = f2bf(agg[mt * 4 + nt][r]);
                }
    }
}

// ---------------------------------------------------------------- launch
extern "C" void kernel_launch(void* const* d_in, const int* in_sizes, int n_in,
                              void* d_out, int out_size, void* d_ws, size_t ws_size,
                              hipStream_t stream)
{
    const float* edge_x = (const float*)d_in[0];
    const float* W1 = (const float*)d_in[1];
    const float* b1 = (const float*)d_in[2];
    const float* W2 = (const float*)d_in[3];
    const float* b2 = (const float*)d_in[4];
    const float* Wo = (const float*)d_in[5];
    const float* bo = (const float*)d_in[6];

    const size_t fixed = 4194304u + 131072u * 2 + 393216u + 2097152u * 2; // Xt+Wt12+Wto+e8s
    const size_t need2 = (size_t)8192 * 1280 * 2 + fixed;
    const int js = (ws_size >= need2) ? 2 : 1;
    const int H = 256 + 2 * js * 256;              // 1280 or 768

    char* ws = (char*)d_ws;
    short* h    = (short*)ws;
    short* Xt   = (short*)(ws + (size_t)8192 * H * 2);
    short* Wt1  = (short*)((char*)Xt + 4194304);
    short* Wt2  = (short*)((char*)Wt1 + 131072);
    short* Wto  = (short*)((char*)Wt2 + 131072);   // 768 x 256 bf16
    char*  e1f8 = (char*)Wto + 393216;
    char*  e2f8 = e1f8 + 2097152;

    prep_all<<<dim3(256, 10), dim3(32, 8), 0, stream>>>(
        edge_x, h, H, Xt, W1, W2, Wo, Wt1, Wt2, Wto);

    // e1/e2 GEMMs -> fp8 shadows directly (one dispatch, grid.z)
    gemm_bias_relu<<<dim3(128, 4, 2), 256, 0, stream>>>(
        h, H, Wt1, Wt2, 256, b1, b2, e1f8, e2f8, 2, 256, 0);
    // 64-row j-tiles: (8192/64)/js per split
    fused_simagg<<<dim3(128, 2, js), 512, 0, stream>>>(e1f8, e2f8, Xt, h, H, 128 / js);
    // final GEMM: K=768 with partial-pair reduction during staging (js==2)
    gemm_bias_relu<<<dim3(128, 4, 1), 256, 0, stream>>>(
        h, H, Wto, Wto, 768, bo, bo, (float*)d_out, (float*)d_out, 0, 256, js == 2);
}

// Round 13
// 230.174 us; speedup vs baseline: 1.1325x; 1.0290x over previous
//
#include <hip/hip_runtime.h>
#include <hip/hip_bf16.h>

// MPNN fused pipeline. R13 = R12 + DMA-staged aux GEMMs:
//  - h (edge part + fused-consumer epilogue) and Wt1/Wt2/Wto are stored
//    with a 16B-granule XOR swizzle per 64-col block (granule g of row r at
//    slot g^(r&7)), so gemm_bias_relu stages As/Bs with pure
//    global_load_lds(16B) -> no VGPR round-trip, no staging VALU (m97
//    mechanism applied to the short-K aux GEMMs, which are staging-bound).
//  - final GEMM's pairadd columns (k0>=256) keep VGPR load+add+ds_write,
//    reading swizzled granules with the same slot math.
//  - fused_simagg unchanged (R9 config, latency floor at the 128-reg /
//    4-waves-per-SIMD bracket) except the epilogue column permutation.
// Arithmetic bit-identical to R12 -> absmax must stay exactly 1.625.

typedef short bf16x8  __attribute__((ext_vector_type(8)));
typedef short short4v __attribute__((ext_vector_type(4)));
typedef float f32x4   __attribute__((ext_vector_type(4)));

__device__ inline short f2bf(float x) {                // fp32 -> bf16 RNE
    unsigned u = __builtin_bit_cast(unsigned, x);
    return (short)((u + 0x7fffu + ((u >> 16) & 1u)) >> 16);
}
__device__ inline float bf2f(short b) {
    return __builtin_bit_cast(float, (unsigned)((unsigned short)b) << 16);
}
__device__ inline void cp16_async(const char* g, char* l) {
    __builtin_amdgcn_global_load_lds(
        (const __attribute__((address_space(1))) unsigned int*)g,
        (__attribute__((address_space(3))) unsigned int*)l, 16, 0, 0);
}

// ------------------------------------------------------------------ prep_all
// grid (256,10), block (32,8):
//   y<8 : edge_x fp32 -> bf16 h[:,0:256] (SWIZZLED per 64-col block)
//         + Xt [256][8192] (raw).
//   y>=8: weight tile -> Wt (SWIZZLED per 64-col k-block).
__global__ void prep_all(const float* __restrict__ X, short* __restrict__ h,
                         int ldh, short* __restrict__ Xt,
                         const float* __restrict__ W1, const float* __restrict__ W2,
                         const float* __restrict__ Wo,
                         short* __restrict__ Wt1, short* __restrict__ Wt2,
                         short* __restrict__ Wto)
{
    __shared__ short tile[32][33];
    const int tx = threadIdx.x, ty = threadIdx.y;      // 32 x 8
    if (blockIdx.y < 8) {
        const int r0 = blockIdx.x * 32, c0 = blockIdx.y * 32;
        #pragma unroll
        for (int i = 0; i < 4; ++i) {
            int row = ty + i * 8;
            short b = f2bf(X[(size_t)(r0 + row) * 256 + c0 + tx]);
            tile[row][tx] = b;
            int slot = ((((c0 & 32) + tx) >> 3) ^ ((r0 + row) & 7));
            h[(size_t)(r0 + row) * ldh + (c0 & ~63) + slot * 8 + (tx & 7)] = b;
        }
        __syncthreads();
        #pragma unroll
        for (int i = 0; i < 4; ++i) {
            int row = ty + i * 8;
            Xt[(size_t)(c0 + row) * 8192 + r0 + tx] = tile[tx][row];
        }
    } else {
        int tw = (blockIdx.y - 8) * 256 + blockIdx.x;
        if (tw >= 320) return;
        const float* src; short* dst; int ldwt, k_off, kx, ny;
        if (tw < 64)       { src = W1; dst = Wt1; ldwt = 256; k_off = 0;
                             kx = tw >> 3; ny = tw & 7; }
        else if (tw < 128) { int u = tw - 64; src = W2; dst = Wt2; ldwt = 256;
                             k_off = 0; kx = u >> 3; ny = u & 7; }
        else               { int u = tw - 128; int g = u >> 6; int rem = u & 63;
                             src = Wo + (size_t)g * 256 * 256; dst = Wto;
                             ldwt = 768; k_off = g * 256;
                             kx = rem >> 3; ny = rem & 7; }
        const int k0 = kx * 32, n0 = ny * 32;
        #pragma unroll
        for (int i = 0; i < 4; ++i) {
            int row = ty + i * 8;
            tile[row][tx] = f2bf(src[(size_t)(k0 + row) * 256 + n0 + tx]);
        }
        __syncthreads();
        #pragma unroll
        for (int i = 0; i < 4; ++i) {
            int row = ty + i * 8;
            int n = n0 + row;
            int slot = ((((k0 & 32) + tx) >> 3) ^ (n & 7));
            dst[(size_t)n * ldwt + k_off + (k0 & ~63) + slot * 8 + (tx & 7)] =
                tile[tx][row];
        }
    }
}

// -------------------------------------------------------- gemm_bias_relu
// A and Bt are granule-swizzled per 64-col block -> As/Bs staged by DMA.
// out_mode: 0 = fp32 plain store; 2 = fp8-e4m3 granule-swizzled shadow.
// pairadd: A col c (c>=256) = h[cc] + h[cc+256], cc = c + (c<512 ? 0 : 256)
//          (manual VGPR path, reads swizzled granules).
__global__ __launch_bounds__(256, 1)
void gemm_bias_relu(const short* __restrict__ A, int lda,
                    const short* __restrict__ Bt0, const short* __restrict__ Bt1,
                    int K,
                    const float* __restrict__ bias0, const float* __restrict__ bias1,
                    void* __restrict__ out0, void* __restrict__ out1,
                    int out_mode, int ldo, int pairadd)
{
    const short* Bt   = blockIdx.z ? Bt1   : Bt0;
    const float* bias = blockIdx.z ? bias1 : bias0;
    void*        outp = blockIdx.z ? out1  : out0;

    const int m0 = blockIdx.x * 64, n0 = blockIdx.y * 64;
    const int t = threadIdx.x;
    const int w = t >> 6, l = t & 63, lr = l & 15, q = l >> 4;
    const int wub = t & ~63;                   // wave-uniform thread base

    __shared__ __attribute__((aligned(16))) short As[64 * 64];
    __shared__ __attribute__((aligned(16))) short Bs[64 * 64];

    f32x4 acc[4];
    #pragma unroll
    for (int i = 0; i < 4; ++i) acc[i] = f32x4{0.f, 0.f, 0.f, 0.f};

    for (int k0 = 0; k0 < K; k0 += 64) {
        __syncthreads();
        // Bs: always DMA (Bt swizzled; slot lands where the reads expect)
        #pragma unroll
        for (int it = 0; it < 2; ++it) {
            int idx = it * 256 + t;
            int r = idx >> 3, s = idx & 7;
            cp16_async((const char*)(Bt + (size_t)(n0 + r) * K + k0) + s * 16,
                       (char*)Bs + (size_t)(it * 256 + wub) * 16);
        }
        if (!pairadd || k0 < 256) {
            // As: DMA
            #pragma unroll
            for (int it = 0; it < 2; ++it) {
                int idx = it * 256 + t;
                int r = idx >> 3, s = idx & 7;
                cp16_async((const char*)(A + (size_t)(m0 + r) * lda + k0) + s * 16,
                           (char*)As + (size_t)(it * 256 + wub) * 16);
            }
        } else {
            // As: manual pairadd from swizzled granules
            for (int i = t; i < 512; i += 256) {
                int r = i >> 3, g = i & 7;
                int c = k0 + g * 8;
                int cc = (c < 512) ? c : c + 256;
                int slot = g ^ (r & 7);        // (m0+r)&7 == r&7 (m0 % 64 == 0)
                const short* base = A + (size_t)(m0 + r) * lda + (cc & ~63) + slot * 8;
                bf16x8 x = *(const bf16x8*)(base);
                bf16x8 y = *(const bf16x8*)(base + 256);
                bf16x8 av;
                #pragma unroll
                for (int e = 0; e < 8; ++e) av[e] = f2bf(bf2f(x[e]) + bf2f(y[e]));
                *(bf16x8*)&As[r * 64 + (slot << 3)] = av;
            }
        }
        __syncthreads();
        #pragma unroll
        for (int ks = 0; ks < 2; ++ks) {
            int arow = w * 16 + lr;
            bf16x8 af = *(const bf16x8*)&As[arow * 64 + (((ks*4 + q) ^ (arow & 7)) << 3)];
            #pragma unroll
            for (int nt = 0; nt < 4; ++nt) {
                int brow = nt * 16 + lr;
                bf16x8 bfg = *(const bf16x8*)&Bs[brow * 64 + (((ks*4 + q) ^ (brow & 7)) << 3)];
                acc[nt] = __builtin_amdgcn_mfma_f32_16x16x32_bf16(af, bfg, acc[nt], 0, 0, 0);
            }
        }
    }

    if (out_mode == 0) {
        #pragma unroll
        for (int nt = 0; nt < 4; ++nt)
            #pragma unroll
            for (int r = 0; r < 4; ++r) {
                int m = m0 + w * 16 + q * 4 + r;  // C/D: row = quad*4 + reg
                int n = n0 + nt * 16 + lr;        //      col = lane & 15
                float v = acc[nt][r] + bias[n];
                ((float*)outp)[(size_t)m * ldo + n] = v > 0.f ? v : 0.f;
            }
    } else {
        // fp8 epilogue: restage relu(acc+bias) as bf16 in As (unswizzled),
        // then pack 8-value granules into the swizzled global shadow.
        __syncthreads();                          // As K-loop readers done
        #pragma unroll
        for (int nt = 0; nt < 4; ++nt)
            #pragma unroll
            for (int r = 0; r < 4; ++r) {
                int mloc = w * 16 + q * 4 + r;
                int nloc = nt * 16 + lr;
                float v = acc[nt][r] + bias[n0 + nloc];
                As[mloc * 64 + nloc] = f2bf(v > 0.f ? v : 0.f);
            }
        __syncthreads();
        char* o = (char*)outp;
        for (int i = t; i < 512; i += 256) {      // 64 rows x 8 granules
            int rloc = i >> 3, g = i & 7;
            bf16x8 vv = *(const bf16x8*)&As[rloc * 64 + g * 8];
            float f[8];
            #pragma unroll
            for (int e = 0; e < 8; ++e) f[e] = bf2f(vv[e]);
            int a = __builtin_amdgcn_cvt_pk_fp8_f32(f[0], f[1], 0, false);
            a     = __builtin_amdgcn_cvt_pk_fp8_f32(f[2], f[3], a, true);
            int b = __builtin_amdgcn_cvt_pk_fp8_f32(f[4], f[5], 0, false);
            b     = __builtin_amdgcn_cvt_pk_fp8_f32(f[6], f[7], b, true);
            int m = m0 + rloc;
            int gg = (n0 >> 3) + g;
            int slot = (gg & 24) | ((gg & 7) ^ (m & 7));
            int2 r2{a, b};
            *(int2*)(o + (size_t)m * 256 + slot * 8) = r2;
        }
    }
}

// ---------------------------------------------------------- fused_simagg
// R9-proven config: 512 thr, waves 0-3 produce P(jt) (fp8 QK) into
// Ps[jt&1]; waves 4-7 consume P(jt-1) with V from Xt. 1 barrier/tile.
// Epilogue writes h agg columns SWIZZLED per 64-col block.
__global__ __launch_bounds__(512, 4)
void fused_simagg(const char* __restrict__ e1f8, const char* __restrict__ e2f8,
                  const short* __restrict__ Xt, short* __restrict__ h,
                  int ldh, int tiles_per_split)
{
    // XCD swizzle: grid (128,2,2) -> each (sim,jz) quadrant on 2 fixed XCDs.
    int sim, jz, mx;
    if (gridDim.x == 128 && gridDim.z == 2) {
        int flat = blockIdx.x + 128 * (blockIdx.y + 2 * blockIdx.z);
        int xcd = flat & 7, slot = flat >> 3;
        int quad = xcd >> 1;
        sim = quad >> 1; jz = quad & 1;
        mx = slot + (xcd & 1) * 64;
    } else { sim = blockIdx.y; jz = blockIdx.z; mx = blockIdx.x; }

    const char* e8 = sim ? e2f8 : e1f8;
    const int m0 = mx * 64;
    const int t = threadIdx.x;
    const int w = t >> 6, l = t & 63, lr = l & 15, q = l >> 4;

    __shared__ __attribute__((aligned(16))) char  Ks8[2][64 * 256]; // 32 KB
    __shared__ __attribute__((aligned(16))) short Ps[2][64 * 64];   // 16 KB

    const int jbase = jz * tiles_per_split;
    const int T = tiles_per_split;

    if (w < 4) {
        // ============ producer: S^T = K.Q^T (fp8) -> Ps (bf16) ============
        const int mh = (w & 1) * 32;           // m-half of this wave
        const int jh = (w >> 1) * 32;          // j-half of this wave
        const int wub = t & ~63;               // wave-uniform base (t 0..255)

        long qf8[2][8];                        // 32 VGPRs: fp8 Q frags
        #pragma unroll
        for (int ms = 0; ms < 2; ++ms) {
            const int mrow = m0 + mh + ms * 16 + lr;
            const char* qrow = e8 + (size_t)mrow * 256;
            #pragma unroll
            for (int kc = 0; kc < 8; ++kc) {
                int g = kc * 4 + q;
                int slot = (g & 24) | ((g & 7) ^ (mrow & 7));
                qf8[ms][kc] = *(const long*)(qrow + slot * 8);
            }
        }
        // prologue: stage tile 0 (16 KB = 1024 granules over 256 threads)
        {
            const char* src = e8 + (size_t)(jbase * 64) * 256;
            #pragma unroll
            for (int it = 0; it < 4; ++it)
                cp16_async(src + (size_t)(it * 256 + t) * 16,
                           &Ks8[0][(size_t)(it * 256 + wub) * 16]);
        }
        __syncthreads();                       // barrier 0 (matches consumer)

        for (int jt = 0; jt <= T; ++jt) {
            if (jt < T) {
                const int cur = jt & 1;
                const int j0 = (jbase + jt) * 64;
                if (jt + 1 < T) {              // async prefetch of next K tile
                    const char* src = e8 + (size_t)(j0 + 64) * 256;
                    #pragma unroll
                    for (int it = 0; it < 4; ++it)
                        cp16_async(src + (size_t)(it * 256 + t) * 16,
                                   &Ks8[cur ^ 1][(size_t)(it * 256 + wub) * 16]);
                }
                const char* Kb = &Ks8[cur][0];
                f32x4 s[2][2];                 // [js2][ms]
                #pragma unroll
                for (int a = 0; a < 2; ++a)
                    #pragma unroll
                    for (int b = 0; b < 2; ++b) s[a][b] = f32x4{0.f, 0.f, 0.f, 0.f};
                #pragma unroll
                for (int kc = 0; kc < 8; ++kc) {
                    #pragma unroll
                    for (int js2 = 0; js2 < 2; ++js2) {
                        int row = jh + js2 * 16 + lr;
                        int g = kc * 4 + q;
                        int slot = (g & 24) | ((g & 7) ^ (row & 7));
                        long kf = *(const long*)&Kb[row * 256 + slot * 8];
                        #pragma unroll
                        for (int ms = 0; ms < 2; ++ms)
                            s[js2][ms] = __builtin_amdgcn_mfma_f32_16x16x32_fp8_fp8(
                                kf, qf8[ms][kc], s[js2][ms], 0, 0, 0);
                    }
                }
                // P scatter: 4 consecutive j at fixed m -> one aligned b64
                #pragma unroll
                for (int js2 = 0; js2 < 2; ++js2)
                    #pragma unroll
                    for (int ms = 0; ms < 2; ++ms) {
                        int mloc = mh + ms * 16 + lr;
                        int jj = jh + js2 * 16 + q * 4;
                        int off = mloc * 64 + (((jj >> 3) ^ (mloc & 7)) << 3) + (jj & 7);
                        short4v pk = { f2bf(s[js2][ms][0] * (1.0f/256.0f)),
                                       f2bf(s[js2][ms][1] * (1.0f/256.0f)),
                                       f2bf(s[js2][ms][2] * (1.0f/256.0f)),
                                       f2bf(s[js2][ms][3] * (1.0f/256.0f)) };
                        *(short4v*)&Ps[cur][off] = pk;
                    }
            }
            __syncthreads();                   // barrier per tile
        }
    } else {
        // ============ consumer: agg += P(jt-1) x V (R9 config) ============
        const int wv = w - 4;                  // n-strip selector 0..3
        f32x4 agg[16];                         // 64 AGPRs
        #pragma unroll
        for (int i = 0; i < 16; ++i) agg[i] = f32x4{0.f, 0.f, 0.f, 0.f};

        __syncthreads();                       // barrier 0 (matches producer)

        for (int jt = 0; jt <= T; ++jt) {
            if (jt >= 1) {
                const int p = (jt - 1) & 1;
                const int j0 = (jbase + jt - 1) * 64;
                #pragma unroll
                for (int ks = 0; ks < 2; ++ks) {
                    bf16x8 pf[4], vfr[4];
                    #pragma unroll
                    for (int nt = 0; nt < 4; ++nt) {
                        int n = wv * 64 + nt * 16 + lr;
                        vfr[nt] = *(const bf16x8*)(Xt + (size_t)n * 8192 + j0 + (ks * 4 + q) * 8);
                    }
                    #pragma unroll
                    for (int mt = 0; mt < 4; ++mt) {
                        int row = mt * 16 + lr;
                        pf[mt] = *(const bf16x8*)&Ps[p][row * 64 + (((ks*4 + q) ^ (row & 7)) << 3)];
                    }
                    #pragma unroll
                    for (int nt = 0; nt < 4; ++nt)
                        #pragma unroll
                        for (int mt = 0; mt < 4; ++mt)
                            agg[mt * 4 + nt] = __builtin_amdgcn_mfma_f32_16x16x32_bf16(
                                pf[mt], vfr[nt], agg[mt * 4 + nt], 0, 0, 0);
                }
            }
            __syncthreads();                   // barrier per tile
        }

        const int colbase = 256 + (sim * gridDim.z + jz) * 256;
        #pragma unroll
        for (int mt = 0; mt < 4; ++mt)
            #pragma unroll
            for (int nt = 0; nt < 4; ++nt)
                #pragma unroll
                for (int r = 0; r < 4; ++r) {
                    int m = m0 + mt * 16 + q * 4 + r;
                    int off = nt * 16 + lr;                    // 0..63 in block
                    int slot = (off >> 3) ^ (m & 7);
                    h[(size_t)m * ldh + colbase + wv * 64 + slot * 8 + (lr & 7)]
                        = f2bf(agg[mt * 4 + nt][r]);
                }
    }
}

// ---------------------------------------------------------------- launch
extern "C" void kernel_launch(void* const* d_in, const int* in_sizes, int n_in,
                              void* d_out, int out_size, void* d_ws, size_t ws_size,
                              hipStream_t stream)
{
    const float* edge_x = (const float*)d_in[0];
    const float* W1 = (const float*)d_in[1];
    const float* b1 = (const float*)d_in[2];
    const float* W2 = (const float*)d_in[3];
    const float* b2 = (const float*)d_in[4];
    const float* Wo = (const float*)d_in[5];
    const float* bo = (const float*)d_in[6];

    const size_t fixed = 4194304u + 131072u * 2 + 393216u + 2097152u * 2; // Xt+Wt12+Wto+e8s
    const size_t need2 = (size_t)8192 * 1280 * 2 + fixed;
    const int js = (ws_size >= need2) ? 2 : 1;
    const int H = 256 + 2 * js * 256;              // 1280 or 768

    char* ws = (char*)d_ws;
    short* h    = (short*)ws;
    short* Xt   = (short*)(ws + (size_t)8192 * H * 2);
    short* Wt1  = (short*)((char*)Xt + 4194304);
    short* Wt2  = (short*)((char*)Wt1 + 131072);
    short* Wto  = (short*)((char*)Wt2 + 131072);   // 768 x 256 bf16
    char*  e1f8 = (char*)Wto + 393216;
    char*  e2f8 = e1f8 + 2097152;

    prep_all<<<dim3(256, 10), dim3(32, 8), 0, stream>>>(
        edge_x, h, H, Xt, W1, W2, Wo, Wt1, Wt2, Wto);

    // e1/e2 GEMMs -> fp8 shadows directly (one dispatch, grid.z)
    gemm_bias_relu<<<dim3(128, 4, 2), 256, 0, stream>>>(
        h, H, Wt1, Wt2, 256, b1, b2, e1f8, e2f8, 2, 256, 0);
    // 64-row j-tiles: (8192/64)/js per split
    fused_simagg<<<dim3(128, 2, js), 512, 0, stream>>>(e1f8, e2f8, Xt, h, H, 128 / js);
    // final GEMM: K=768 with partial-pair reduction during staging (js==2)
    gemm_bias_relu<<<dim3(128, 4, 1), 256, 0, stream>>>(
        h, H, Wto, Wto, 768, bo, bo, (float*)d_out, (float*)d_out, 0, 256, js == 2);
}